// Round 2
// baseline (96.612 us; speedup 1.0000x reference)
//
#include <hip/hip_runtime.h>

// loss = 1 - mean_over_rows( all_c(real == (pred>0.5)) ), real/pred f32 [128,8192,8]
// C=8 contiguous -> one float4 = half a row. Unit-stride float4 indexing across
// the wave; halves of row k land in lanes 2k,2k+1 -> paired via ballot bits.
// Two dispatches, no fences, no dependence on d_ws poison value (all partial
// slots are written every launch).
//
// R5 change: __builtin_nontemporal_load on the streaming input reads (emits
// `nt` on global_load_dwordx4). Inputs are evicted from L2/L3 by the harness's
// 256 MiB poison fill each iteration, so every line is a cold miss; nt marks
// the incoming lines evict-first so the read stream doesn't pay L2
// allocation/dirty-replacement interference against the just-poisoned lines.
// R4's occupancy A/B was MLP-confounded (per-CU in-flight bytes identical in
// both configs) -- this is the remaining streaming-read lever.

#define N_ROWS (128 * 8192)              // 1,048,576 rows
#define N_F4   (N_ROWS * 2)              // 2,097,152 float4s per input
#define BLOCK  256
#define ITERS  4
#define GRID   (N_F4 / (BLOCK * ITERS))  // 2048 blocks, exact

typedef float f4_t __attribute__((ext_vector_type(4)));

__global__ __launch_bounds__(BLOCK, 8) void row_match_count(
    const f4_t* __restrict__ real4,
    const f4_t* __restrict__ pred4,
    unsigned int* __restrict__ partials) {
  const int base = blockIdx.x * (BLOCK * ITERS) + threadIdx.x;

  // Coalesced 16B nontemporal loads; all 8 issued before any compare so
  // 128 B/thread of misses are in flight together.
  f4_t r[ITERS], p[ITERS];
#pragma unroll
  for (int j = 0; j < ITERS; ++j) {
    r[j] = __builtin_nontemporal_load(real4 + base + j * BLOCK);
    p[j] = __builtin_nontemporal_load(pred4 + base + j * BLOCK);
  }

  unsigned int cnt = 0;
#pragma unroll
  for (int j = 0; j < ITERS; ++j) {
    // real is exactly 0/1: (real == (pred>0.5)) <=> ((real>0.5)==(pred>0.5))
    bool ok = ((r[j].x > 0.5f) == (p[j].x > 0.5f)) &&
              ((r[j].y > 0.5f) == (p[j].y > 0.5f)) &&
              ((r[j].z > 0.5f) == (p[j].z > 0.5f)) &&
              ((r[j].w > 0.5f) == (p[j].w > 0.5f));
    // 64-bit wave ballot: bit i = lane i's half-row ok. Row ok = both halves ok.
    unsigned long long m = __ballot(ok);
    m &= (m >> 1);
    m &= 0x5555555555555555ULL;
    cnt += (unsigned int)__popcll(m);  // wave-uniform rows-matched this iter
  }

  // Combine the 4 waves of the block; one partial per block, no global atomic.
  __shared__ unsigned int wsum[BLOCK / 64];
  const int lane = threadIdx.x & 63;
  const int wave = threadIdx.x >> 6;
  if (lane == 0) wsum[wave] = cnt;
  __syncthreads();
  if (threadIdx.x == 0)
    partials[blockIdx.x] = wsum[0] + wsum[1] + wsum[2] + wsum[3];
}

__global__ __launch_bounds__(256) void finalize_loss(
    const unsigned int* __restrict__ partials, float* __restrict__ out) {
  const int t = threadIdx.x;
  unsigned int s = 0;
#pragma unroll
  for (int k = 0; k < GRID / 256; ++k) s += partials[t + k * 256];  // 8 coalesced loads
#pragma unroll
  for (int off = 32; off > 0; off >>= 1) s += __shfl_down(s, off, 64);

  __shared__ unsigned int wsum[4];
  if ((t & 63) == 0) wsum[t >> 6] = s;
  __syncthreads();
  if (t == 0)
    out[0] = 1.0f - (float)(wsum[0] + wsum[1] + wsum[2] + wsum[3]) *
                        (1.0f / (float)N_ROWS);
}

extern "C" void kernel_launch(void* const* d_in, const int* in_sizes, int n_in,
                              void* d_out, int out_size, void* d_ws, size_t ws_size,
                              hipStream_t stream) {
  const f4_t* real4 = (const f4_t*)d_in[0];
  const f4_t* pred4 = (const f4_t*)d_in[1];
  unsigned int* partials = (unsigned int*)d_ws;  // GRID * 4 B = 8 KB scratch
  float* out = (float*)d_out;

  // Every partial slot is written by its block -> no memset node needed.
  row_match_count<<<GRID, BLOCK, 0, stream>>>(real4, pred4, partials);
  finalize_loss<<<1, 256, 0, stream>>>(partials, out);
}

// Round 3
// 91.161 us; speedup vs baseline: 1.0598x; 1.0598x over previous
//
#include <hip/hip_runtime.h>

// loss = 1 - mean_over_rows( all_c(real == (pred>0.5)) ), real/pred f32 [128,8192,8]
// C=8 contiguous -> one float4 = half a row. Unit-stride float4 indexing across
// the wave; halves of row k land in lanes 2k,2k+1 -> paired via ballot bits.
// Two dispatches, no fences, no dependence on d_ws poison value (all partial
// slots are written every launch).
//
// R6: pure revert of R5's nontemporal loads (measured -3.7 us: nt demotes the
// TCC path for a one-touch stream; there was no L2 replacement interference to
// remove -- fills and reads serialize across graph nodes). This is the
// best-measured structure: 92.90 us total, reproduced twice to +/-0.01 us.
// Lever ledger (all measured): 16B/lane coalesced loads OK; 16 vs 32 waves/CU
// identical (per-CU bytes-in-flight equal -> MLP-saturated either way);
// nt loads regress; ballot reduction, no atomics, 2-dispatch minimum.

#define N_ROWS (128 * 8192)              // 1,048,576 rows
#define N_F4   (N_ROWS * 2)              // 2,097,152 float4s per input
#define BLOCK  256
#define ITERS  4
#define GRID   (N_F4 / (BLOCK * ITERS))  // 2048 blocks, exact

__global__ __launch_bounds__(BLOCK, 8) void row_match_count(
    const float4* __restrict__ real4,
    const float4* __restrict__ pred4,
    unsigned int* __restrict__ partials) {
  const int base = blockIdx.x * (BLOCK * ITERS) + threadIdx.x;

  // Coalesced 16B loads; all 8 issued before any compare so 128 B/thread of
  // misses are in flight together.
  float4 r[ITERS], p[ITERS];
#pragma unroll
  for (int j = 0; j < ITERS; ++j) r[j] = real4[base + j * BLOCK];
#pragma unroll
  for (int j = 0; j < ITERS; ++j) p[j] = pred4[base + j * BLOCK];

  unsigned int cnt = 0;
#pragma unroll
  for (int j = 0; j < ITERS; ++j) {
    // real is exactly 0/1: (real == (pred>0.5)) <=> ((real>0.5)==(pred>0.5))
    bool ok = ((r[j].x > 0.5f) == (p[j].x > 0.5f)) &&
              ((r[j].y > 0.5f) == (p[j].y > 0.5f)) &&
              ((r[j].z > 0.5f) == (p[j].z > 0.5f)) &&
              ((r[j].w > 0.5f) == (p[j].w > 0.5f));
    // 64-bit wave ballot: bit i = lane i's half-row ok. Row ok = both halves ok.
    unsigned long long m = __ballot(ok);
    m &= (m >> 1);
    m &= 0x5555555555555555ULL;
    cnt += (unsigned int)__popcll(m);  // wave-uniform rows-matched this iter
  }

  // Combine the 4 waves of the block; one partial per block, no global atomic.
  __shared__ unsigned int wsum[BLOCK / 64];
  const int lane = threadIdx.x & 63;
  const int wave = threadIdx.x >> 6;
  if (lane == 0) wsum[wave] = cnt;
  __syncthreads();
  if (threadIdx.x == 0)
    partials[blockIdx.x] = wsum[0] + wsum[1] + wsum[2] + wsum[3];
}

__global__ __launch_bounds__(256) void finalize_loss(
    const unsigned int* __restrict__ partials, float* __restrict__ out) {
  const int t = threadIdx.x;
  unsigned int s = 0;
#pragma unroll
  for (int k = 0; k < GRID / 256; ++k) s += partials[t + k * 256];  // 8 coalesced loads
#pragma unroll
  for (int off = 32; off > 0; off >>= 1) s += __shfl_down(s, off, 64);

  __shared__ unsigned int wsum[4];
  if ((t & 63) == 0) wsum[t >> 6] = s;
  __syncthreads();
  if (t == 0)
    out[0] = 1.0f - (float)(wsum[0] + wsum[1] + wsum[2] + wsum[3]) *
                        (1.0f / (float)N_ROWS);
}

extern "C" void kernel_launch(void* const* d_in, const int* in_sizes, int n_in,
                              void* d_out, int out_size, void* d_ws, size_t ws_size,
                              hipStream_t stream) {
  const float4* real4 = (const float4*)d_in[0];
  const float4* pred4 = (const float4*)d_in[1];
  unsigned int* partials = (unsigned int*)d_ws;  // GRID * 4 B = 8 KB scratch
  float* out = (float*)d_out;

  // Every partial slot is written by its block -> no memset node needed.
  row_match_count<<<GRID, BLOCK, 0, stream>>>(real4, pred4, partials);
  finalize_loss<<<1, 256, 0, stream>>>(partials, out);
}